// Round 3
// baseline (379.203 us; speedup 1.0000x reference)
//
#include <hip/hip_runtime.h>

// out[m][o] = bias[o] + sum_r t[m][r]*U[o][r],  t[m][r] = sum_k x[m][k]*V[k][r]
// x[8192][4096] fp32, U[4096][64], V[4096][64], bias[4096]
#define IN_F    4096
#define OUT_F   4096
#define RANK    64
#define M_TOTAL 8192
#define M_TILE  16
#define BLOCK   512
#define NWAVES  8
#define KSPLIT  4
#define XV_MT   32

using short8  = __attribute__((ext_vector_type(8))) short;
using float4v = __attribute__((ext_vector_type(4))) float;

#define MFMA16(A, B, C) __builtin_amdgcn_mfma_f32_16x16x32_bf16((A), (B), (C), 0, 0, 0)

// Exact split: x = f32(hi) + r, lo = trunc_bf16(r). Error of (hi,lo) pair ~2^-16 rel.
__device__ __forceinline__ void split2(float x, short& h, short& l) {
    unsigned u = __float_as_uint(x);
    unsigned t = u & 0xffff0000u;
    h = (short)(t >> 16);
    float r = x - __uint_as_float(t);
    l = (short)(__float_as_uint(r) >> 16);
}

__device__ __forceinline__ void split_f4x2(float4 a, float4 b, short8& hi, short8& lo) {
    short h0,h1,h2,h3,h4,h5,h6,h7, l0,l1,l2,l3,l4,l5,l6,l7;
    split2(a.x,h0,l0); split2(a.y,h1,l1); split2(a.z,h2,l2); split2(a.w,h3,l3);
    split2(b.x,h4,l4); split2(b.y,h5,l5); split2(b.z,h6,l6); split2(b.w,h7,l7);
    hi = (short8){h0,h1,h2,h3,h4,h5,h6,h7};
    lo = (short8){l0,l1,l2,l3,l4,l5,l6,l7};
}

// ============================================================================
// V3 PATH: prep -> xv2 (32 waves/CU, K-split blocks) -> reduce_t -> tu2
// ============================================================================

// blocks 0..255:   V[k][r] fp32 -> vt_hi/lo[r][k] bf16 (transposed)
// blocks 256..511: U[o][r] fp32 -> u_hi/lo[o][r] bf16 (layout preserved)
__global__ void prep_uv(const float* __restrict__ V, const float* __restrict__ U,
                        unsigned short* __restrict__ vt_hi, unsigned short* __restrict__ vt_lo,
                        unsigned short* __restrict__ u_hi,  unsigned short* __restrict__ u_lo)
{
    const int b = blockIdx.x;
    const int linear = (b & 255) * 256 + threadIdx.x;   // 0..65535
    short h[4], l[4];
    if (b < 256) {
        const int r  = linear >> 10;                    // 0..63
        const int k0 = (linear & 1023) * 4;             // 0..4092
        #pragma unroll
        for (int i = 0; i < 4; ++i)
            split2(V[(size_t)(k0 + i) * RANK + r], h[i], l[i]);
        const size_t o = (size_t)r * IN_F + k0;
        *(ushort4*)(vt_hi + o) = make_ushort4((unsigned short)h[0], (unsigned short)h[1],
                                              (unsigned short)h[2], (unsigned short)h[3]);
        *(ushort4*)(vt_lo + o) = make_ushort4((unsigned short)l[0], (unsigned short)l[1],
                                              (unsigned short)l[2], (unsigned short)l[3]);
    } else {
        const int idx = linear * 4;                     // contiguous over U
        const float4 u4 = *(const float4*)(U + idx);
        split2(u4.x, h[0], l[0]); split2(u4.y, h[1], l[1]);
        split2(u4.z, h[2], l[2]); split2(u4.w, h[3], l[3]);
        *(ushort4*)(u_hi + idx) = make_ushort4((unsigned short)h[0], (unsigned short)h[1],
                                               (unsigned short)h[2], (unsigned short)h[3]);
        *(ushort4*)(u_lo + idx) = make_ushort4((unsigned short)l[0], (unsigned short)l[1],
                                               (unsigned short)l[2], (unsigned short)l[3]);
    }
}

// t_part[kq] = x[:, kq*1024:+1024] @ V-slice. Grid 1024 = 4 blocks/CU exactly,
// 32 waves/CU (100% occ target). Block: 32 rows, 8 waves = 2 m-subs x 4 k-subs.
// kq = bid&3 keeps each vt k-slice resident per-XCD L2 slice set.
__global__ __launch_bounds__(512, 8) void lowrank_xv2(
    const float* __restrict__ x,
    const unsigned short* __restrict__ vt_hi, const unsigned short* __restrict__ vt_lo,
    float* __restrict__ t_part)                         // [KSPLIT][8192][64] fp32
{
    __shared__ float part[KSPLIT][XV_MT][RANK + 4];     // 34816 B -> 4 blocks/CU

    const int tid  = threadIdx.x;
    const int wv   = tid >> 6;      // 0..7
    const int msub = wv >> 2;       // 0..1 (16-row sub-tile)
    const int ksub = wv & 3;        // 0..3 (256-col k sub-slice)
    const int lane = tid & 63;
    const int l15  = lane & 15;
    const int quad = lane >> 4;
    const int kq   = blockIdx.x & 3;
    const int mg   = blockIdx.x >> 2;        // 0..255
    const int m0   = mg * XV_MT;
    const int kbase = kq * 1024 + ksub * 256;

    // A-frag: A[m=l15][k=quad*8+j] from x; B-frag: B[k][r=l15] from vt (16B contig)
    float4v acc[4] = {};
    const float*          xp = x     + (size_t)(m0 + msub * 16 + l15) * IN_F + kbase + quad * 8;
    const unsigned short* vh = vt_hi + (size_t)l15 * IN_F + kbase + quad * 8;
    const unsigned short* vl = vt_lo + (size_t)l15 * IN_F + kbase + quad * 8;

    float4 xa = *(const float4*)(xp);
    float4 xb = *(const float4*)(xp + 4);
    #pragma unroll
    for (int ks = 0; ks < 8; ++ks) {
        const int k0 = ks * 32;
        float4 na = xa, nb = xb;
        if (ks < 7) {                               // 1-ahead x prefetch
            na = *(const float4*)(xp + k0 + 32);
            nb = *(const float4*)(xp + k0 + 36);
        }
        short8 a_hi, a_lo;
        split_f4x2(xa, xb, a_hi, a_lo);
        #pragma unroll
        for (int rt = 0; rt < 4; ++rt) {
            short8 b_hi = *(const short8*)(vh + (size_t)rt * 16 * IN_F + k0);
            short8 b_lo = *(const short8*)(vl + (size_t)rt * 16 * IN_F + k0);
            acc[rt] = MFMA16(a_lo, b_hi, acc[rt]);
            acc[rt] = MFMA16(a_hi, b_lo, acc[rt]);
            acc[rt] = MFMA16(a_hi, b_hi, acc[rt]);
        }
        xa = na; xb = nb;
    }

    // C/D layout: col = l15 (r), row = quad*4 + reg (m within 16)
    #pragma unroll
    for (int rt = 0; rt < 4; ++rt)
        #pragma unroll
        for (int rg = 0; rg < 4; ++rg)
            part[ksub][msub * 16 + quad * 4 + rg][rt * 16 + l15] = acc[rt][rg];
    __syncthreads();

    // Reduce 4 k-sub partials in fp32, write fp32 partial plane (KSPLIT across blocks).
    const int e = tid * 4;                 // 2048 elems / 512 threads = 4 each
    const int m = e >> 6, r = e & 63;
    float4 s = {0.f, 0.f, 0.f, 0.f};
    #pragma unroll
    for (int ks2 = 0; ks2 < KSPLIT; ++ks2) {
        const float4 p4 = *(const float4*)(&part[ks2][m][r]);
        s.x += p4.x; s.y += p4.y; s.z += p4.z; s.w += p4.w;
    }
    *(float4*)(t_part + (size_t)kq * (M_TOTAL * RANK) + (size_t)(m0 + m) * RANK + r) = s;
}

// Sum the 4 fp32 K-partials, split to bf16 hi/lo. 8MB read, 2MB write (~3us).
__global__ void reduce_t(const float* __restrict__ t_part,
                         unsigned short* __restrict__ t_hi, unsigned short* __restrict__ t_lo)
{
    const size_t e = (size_t)(blockIdx.x * 256 + threadIdx.x) * 4;  // grid 512
    float4 s = *(const float4*)(t_part + e);
    #pragma unroll
    for (int p = 1; p < KSPLIT; ++p) {
        const float4 a = *(const float4*)(t_part + (size_t)p * (M_TOTAL * RANK) + e);
        s.x += a.x; s.y += a.y; s.z += a.z; s.w += a.w;
    }
    short h[4], l[4];
    split2(s.x, h[0], l[0]); split2(s.y, h[1], l[1]);
    split2(s.z, h[2], l[2]); split2(s.w, h[3], l[3]);
    *(ushort4*)(t_hi + e) = make_ushort4((unsigned short)h[0], (unsigned short)h[1],
                                         (unsigned short)h[2], (unsigned short)h[3]);
    *(ushort4*)(t_lo + e) = make_ushort4((unsigned short)l[0], (unsigned short)l[1],
                                         (unsigned short)l[2], (unsigned short)l[3]);
}

// out = t @ U^T + bias. Grid 2048 = 8 blocks/CU, 32 waves/CU. Wave owns 16m x 256o.
// u-frags prefetched 1-ahead; t-frags hoisted (loop-invariant).
__global__ __launch_bounds__(256, 8) void lowrank_tu2(
    const unsigned short* __restrict__ t_hi, const unsigned short* __restrict__ t_lo,
    const unsigned short* __restrict__ u_hi, const unsigned short* __restrict__ u_lo,
    const float* __restrict__ bias, float* __restrict__ out)
{
    const int tid  = threadIdx.x;
    const int wv   = tid >> 6;            // 0..3
    const int lane = tid & 63;
    const int l15  = lane & 15;
    const int quad = lane >> 4;
    const int og   = blockIdx.x & 15;     // 16 o-groups of 256
    const int mg   = blockIdx.x >> 4;     // 128 m-groups of 64
    const int m0   = mg * 64 + wv * 16;
    const int o0   = og * 256;

    // A-frags (t) hoisted: loop-invariant over o. A[m=l15][r=ks*32+quad*8+j]
    short8 ta_hi[2], ta_lo[2];
    {
        const unsigned short* tp_h = t_hi + (size_t)(m0 + l15) * RANK + quad * 8;
        const unsigned short* tp_l = t_lo + (size_t)(m0 + l15) * RANK + quad * 8;
        ta_hi[0] = *(const short8*)(tp_h);   ta_hi[1] = *(const short8*)(tp_h + 32);
        ta_lo[0] = *(const short8*)(tp_l);   ta_lo[1] = *(const short8*)(tp_l + 32);
    }

    // B-frag: B[r][o=l15] = u_hi/lo[o][r], 16B contig per lane. o advances 16/iter
    // -> +1024 elems. Prefetch next iter's 4 loads before computing current.
    const unsigned short* up_h = u_hi + (size_t)(o0 + l15) * RANK + quad * 8;
    const unsigned short* up_l = u_lo + (size_t)(o0 + l15) * RANK + quad * 8;
    short8 uh0 = *(const short8*)(up_h);
    short8 uh1 = *(const short8*)(up_h + 32);
    short8 ul0 = *(const short8*)(up_l);
    short8 ul1 = *(const short8*)(up_l + 32);

    #pragma unroll 2
    for (int nt = 0; nt < 16; ++nt) {
        short8 nh0 = uh0, nh1 = uh1, nl0 = ul0, nl1 = ul1;
        if (nt < 15) {
            const int adv = (nt + 1) * 16 * RANK;
            nh0 = *(const short8*)(up_h + adv);
            nh1 = *(const short8*)(up_h + adv + 32);
            nl0 = *(const short8*)(up_l + adv);
            nl1 = *(const short8*)(up_l + adv + 32);
        }
        const int o = o0 + nt * 16 + l15;
        const float bv = bias[o];
        float4v acc = {bv, bv, bv, bv};
        acc = MFMA16(ta_lo[0], uh0, acc);
        acc = MFMA16(ta_hi[0], ul0, acc);
        acc = MFMA16(ta_hi[0], uh0, acc);
        acc = MFMA16(ta_lo[1], uh1, acc);
        acc = MFMA16(ta_hi[1], ul1, acc);
        acc = MFMA16(ta_hi[1], uh1, acc);
        // C/D: col = o (l15), row = quad*4 + reg (m). 64B contiguous per quad-row.
        float* op = out + (size_t)(m0 + quad * 4) * OUT_F + o;
        op[0 * OUT_F] = acc[0];
        op[1 * OUT_F] = acc[1];
        op[2 * OUT_F] = acc[2];
        op[3 * OUT_F] = acc[3];
        uh0 = nh0; uh1 = nh1; ul0 = nl0; ul1 = nl1;
    }
}

// ============================================================================
// LEGACY V2 PATH (verified @327us): xv/tu without K-split, used if ws < 12 MiB
// ============================================================================

__global__ __launch_bounds__(BLOCK, 4) void lowrank_xv(
    const float* __restrict__ x,
    const unsigned short* __restrict__ vt_hi, const unsigned short* __restrict__ vt_lo,
    unsigned short* __restrict__ t_hi, unsigned short* __restrict__ t_lo)
{
    __shared__ float part[NWAVES][M_TILE][RANK + 4];

    const int tid  = threadIdx.x;
    const int wv   = tid >> 6;
    const int lane = tid & 63;
    const int l15  = lane & 15;
    const int quad = lane >> 4;
    const int m0   = blockIdx.x * M_TILE;

    float4v acc[4] = {};
    const float*          xp = x     + (size_t)(m0 + l15) * IN_F + wv * 512 + quad * 8;
    const unsigned short* vh = vt_hi + (size_t)l15 * IN_F + wv * 512 + quad * 8;
    const unsigned short* vl = vt_lo + (size_t)l15 * IN_F + wv * 512 + quad * 8;

    float4 xa = *(const float4*)(xp);
    float4 xb = *(const float4*)(xp + 4);
    #pragma unroll
    for (int ks = 0; ks < 16; ++ks) {
        const int k0 = ks * 32;
        float4 na = xa, nb = xb;
        if (ks < 15) {
            na = *(const float4*)(xp + k0 + 32);
            nb = *(const float4*)(xp + k0 + 36);
        }
        short8 a_hi, a_lo;
        split_f4x2(xa, xb, a_hi, a_lo);
        #pragma unroll
        for (int rt = 0; rt < 4; ++rt) {
            short8 b_hi = *(const short8*)(vh + (size_t)rt * 16 * IN_F + k0);
            short8 b_lo = *(const short8*)(vl + (size_t)rt * 16 * IN_F + k0);
            acc[rt] = MFMA16(a_lo, b_hi, acc[rt]);
            acc[rt] = MFMA16(a_hi, b_lo, acc[rt]);
            acc[rt] = MFMA16(a_hi, b_hi, acc[rt]);
        }
        xa = na; xb = nb;
    }

    #pragma unroll
    for (int rt = 0; rt < 4; ++rt)
        #pragma unroll
        for (int rg = 0; rg < 4; ++rg)
            part[wv][quad * 4 + rg][rt * 16 + l15] = acc[rt][rg];
    __syncthreads();

    const int e = tid * 2;
    const int m = e >> 6, r = e & 63;
    float s0 = 0.f, s1 = 0.f;
    #pragma unroll
    for (int w = 0; w < NWAVES; ++w) { s0 += part[w][m][r]; s1 += part[w][m][r + 1]; }
    short h0, l0, h1, l1;
    split2(s0, h0, l0); split2(s1, h1, l1);
    const size_t off = (size_t)m0 * RANK + e;
    *(ushort2*)(t_hi + off) = make_ushort2((unsigned short)h0, (unsigned short)h1);
    *(ushort2*)(t_lo + off) = make_ushort2((unsigned short)l0, (unsigned short)l1);
}

__global__ __launch_bounds__(256, 4) void lowrank_tu(
    const unsigned short* __restrict__ t_hi, const unsigned short* __restrict__ t_lo,
    const unsigned short* __restrict__ u_hi, const unsigned short* __restrict__ u_lo,
    const float* __restrict__ bias, float* __restrict__ out)
{
    const int tid  = threadIdx.x;
    const int wv   = tid >> 6;
    const int lane = tid & 63;
    const int l15  = lane & 15;
    const int quad = lane >> 4;
    const int og   = blockIdx.x & 7;
    const int mg   = blockIdx.x >> 3;
    const int m0   = mg * 64 + wv * 16;
    const int o0   = og * 512;

    short8 ta_hi[2], ta_lo[2];
    {
        const unsigned short* tp_h = t_hi + (size_t)(m0 + l15) * RANK + quad * 8;
        const unsigned short* tp_l = t_lo + (size_t)(m0 + l15) * RANK + quad * 8;
        ta_hi[0] = *(const short8*)(tp_h);   ta_hi[1] = *(const short8*)(tp_h + 32);
        ta_lo[0] = *(const short8*)(tp_l);   ta_lo[1] = *(const short8*)(tp_l + 32);
    }

    #pragma unroll 2
    for (int nt = 0; nt < 32; ++nt) {
        const int o = o0 + nt * 16 + l15;
        const unsigned short* up_h = u_hi + (size_t)o * RANK + quad * 8;
        const unsigned short* up_l = u_lo + (size_t)o * RANK + quad * 8;
        const float bv = bias[o];
        float4v acc = {bv, bv, bv, bv};
        #pragma unroll
        for (int ks = 0; ks < 2; ++ks) {
            short8 uh = *(const short8*)(up_h + ks * 32);
            short8 ul = *(const short8*)(up_l + ks * 32);
            acc = MFMA16(ta_lo[ks], uh, acc);
            acc = MFMA16(ta_hi[ks], ul, acc);
            acc = MFMA16(ta_hi[ks], uh, acc);
        }
        float* op = out + (size_t)(m0 + quad * 4) * OUT_F + o;
        op[0 * OUT_F] = acc[0];
        op[1 * OUT_F] = acc[1];
        op[2 * OUT_F] = acc[2];
        op[3 * OUT_F] = acc[3];
    }
}

// ---------------- Fallback (fp32) if ws is too small ----------------
__global__ __launch_bounds__(256, 2) void fallback_fp32(
    const float* __restrict__ x, const float* __restrict__ U,
    const float* __restrict__ V, const float* __restrict__ bias,
    float* __restrict__ out)
{
    __shared__ float v_lds[128][RANK];
    __shared__ float t_lds[8][RANK];
    const int tid = threadIdx.x, lane = tid & 63, wave = tid >> 6;
    const int m0 = blockIdx.x * 8;
    float acc0 = 0.f, acc1 = 0.f;
    const size_t row_base = (size_t)(m0 + wave * 2) * IN_F;
    for (int kt = 0; kt < IN_F; kt += 128) {
        const float4* Vg = (const float4*)(V + (size_t)kt * RANK);
        float4* Vs = (float4*)(&v_lds[0][0]);
        #pragma unroll
        for (int i = 0; i < 8; ++i) Vs[tid + 256 * i] = Vg[tid + 256 * i];
        __syncthreads();
        const float* xp = x + row_base + kt;
        #pragma unroll 8
        for (int k = 0; k < 128; k += 4) {
            float v0 = v_lds[k+0][lane], v1 = v_lds[k+1][lane];
            float v2 = v_lds[k+2][lane], v3 = v_lds[k+3][lane];
            float4 xa = *(const float4*)(xp + 0 * IN_F + k);
            float4 xb = *(const float4*)(xp + 1 * IN_F + k);
            acc0 += xa.x*v0 + xa.y*v1 + xa.z*v2 + xa.w*v3;
            acc1 += xb.x*v0 + xb.y*v1 + xb.z*v2 + xb.w*v3;
        }
        __syncthreads();
    }
    t_lds[wave*2+0][lane] = acc0;
    t_lds[wave*2+1][lane] = acc1;
    __syncthreads();
    for (int oc = 0; oc < OUT_F; oc += 1024) {
        const int o4 = oc + tid * 4;
        const float4 b4 = *(const float4*)(bias + o4);
        float4 a0=b4,a1=b4,a2=b4,a3=b4,a4=b4,a5=b4,a6=b4,a7=b4;
        const float* Up = U + (size_t)o4 * RANK;
        #pragma unroll 2
        for (int r0 = 0; r0 < RANK; r0 += 4) {
            const float4 u0 = *(const float4*)(Up + 0*RANK + r0);
            const float4 u1 = *(const float4*)(Up + 1*RANK + r0);
            const float4 u2 = *(const float4*)(Up + 2*RANK + r0);
            const float4 u3 = *(const float4*)(Up + 3*RANK + r0);
            #define P2_STEP(AM, MM) { \
                const float4 t4 = *(const float4*)(&t_lds[MM][r0]); \
                AM.x += t4.x*u0.x + t4.y*u0.y + t4.z*u0.z + t4.w*u0.w; \
                AM.y += t4.x*u1.x + t4.y*u1.y + t4.z*u1.z + t4.w*u1.w; \
                AM.z += t4.x*u2.x + t4.y*u2.y + t4.z*u2.z + t4.w*u2.w; \
                AM.w += t4.x*u3.x + t4.y*u3.y + t4.z*u3.z + t4.w*u3.w; }
            P2_STEP(a0,0) P2_STEP(a1,1) P2_STEP(a2,2) P2_STEP(a3,3)
            P2_STEP(a4,4) P2_STEP(a5,5) P2_STEP(a6,6) P2_STEP(a7,7)
            #undef P2_STEP
        }
        float* op = out + (size_t)m0 * OUT_F + o4;
        *(float4*)(op+0*OUT_F)=a0; *(float4*)(op+1*OUT_F)=a1;
        *(float4*)(op+2*OUT_F)=a2; *(float4*)(op+3*OUT_F)=a3;
        *(float4*)(op+4*OUT_F)=a4; *(float4*)(op+5*OUT_F)=a5;
        *(float4*)(op+6*OUT_F)=a6; *(float4*)(op+7*OUT_F)=a7;
    }
}

extern "C" void kernel_launch(void* const* d_in, const int* in_sizes, int n_in,
                              void* d_out, int out_size, void* d_ws, size_t ws_size,
                              hipStream_t stream) {
    const float* x    = (const float*)d_in[0];
    const float* U    = (const float*)d_in[1];
    const float* V    = (const float*)d_in[2];
    const float* bias = (const float*)d_in[3];
    float* out = (float*)d_out;

    const size_t E = (size_t)RANK * IN_F;        // 262144 (V / U split planes)
    const size_t T = (size_t)M_TOTAL * RANK;     // 524288 (t planes)
    const size_t need_v3 = (E * 4 + T * 2) * sizeof(unsigned short)
                         + (size_t)KSPLIT * T * sizeof(float);           // 12 MiB
    const size_t need_v2 = (E * 4 + T * 2) * sizeof(unsigned short);     // 4 MiB

    if (ws_size >= need_v3) {
        unsigned short* vt_hi = (unsigned short*)d_ws;
        unsigned short* vt_lo = vt_hi + E;
        unsigned short* u_hi  = vt_lo + E;
        unsigned short* u_lo  = u_hi  + E;
        unsigned short* t_hi  = u_lo  + E;
        unsigned short* t_lo  = t_hi  + T;
        float*          t_part = (float*)(t_lo + T);
        prep_uv<<<dim3(512), dim3(256), 0, stream>>>(V, U, vt_hi, vt_lo, u_hi, u_lo);
        lowrank_xv2<<<dim3((M_TOTAL / XV_MT) * KSPLIT), dim3(512), 0, stream>>>(
            x, vt_hi, vt_lo, t_part);
        reduce_t<<<dim3(T / (256 * 4)), dim3(256), 0, stream>>>(t_part, t_hi, t_lo);
        lowrank_tu2<<<dim3((M_TOTAL / 64) * (OUT_F / 256)), dim3(256), 0, stream>>>(
            t_hi, t_lo, u_hi, u_lo, bias, out);
    } else if (ws_size >= need_v2) {
        unsigned short* vt_hi = (unsigned short*)d_ws;
        unsigned short* vt_lo = vt_hi + E;
        unsigned short* u_hi  = vt_lo + E;
        unsigned short* u_lo  = u_hi  + E;
        unsigned short* t_hi  = u_lo  + E;
        unsigned short* t_lo  = t_hi  + T;
        prep_uv<<<dim3(512), dim3(256), 0, stream>>>(V, U, vt_hi, vt_lo, u_hi, u_lo);
        lowrank_xv<<<dim3(M_TOTAL / M_TILE), dim3(BLOCK), 0, stream>>>(
            x, vt_hi, vt_lo, t_hi, t_lo);
        lowrank_tu<<<dim3((M_TOTAL / 64) * (OUT_F / 512)), dim3(256), 0, stream>>>(
            t_hi, t_lo, u_hi, u_lo, bias, out);
    } else {
        fallback_fp32<<<dim3(M_TOTAL / 8), dim3(256), 0, stream>>>(x, U, V, bias, out);
    }
}

// Round 4
// 298.053 us; speedup vs baseline: 1.2723x; 1.2723x over previous
//
#include <hip/hip_runtime.h>

// out[m][o] = bias[o] + sum_r t[m][r]*U[o][r],  t[m][r] = sum_k x[m][k]*V[k][r]
// x[8192][4096] fp32, U[4096][64], V[4096][64], bias[4096]
#define IN_F    4096
#define OUT_F   4096
#define RANK    64
#define M_TOTAL 8192
#define M_TILE  16
#define BLOCK   512
#define NWAVES  8
#define KSPLIT  4

using short8  = __attribute__((ext_vector_type(8))) short;
using float4v = __attribute__((ext_vector_type(4))) float;

#define MFMA16(A, B, C) __builtin_amdgcn_mfma_f32_16x16x32_bf16((A), (B), (C), 0, 0, 0)

// Exact split: x = f32(hi) + r, lo = trunc_bf16(r). Error of (hi,lo) pair ~2^-16 rel.
__device__ __forceinline__ void split2(float x, short& h, short& l) {
    unsigned u = __float_as_uint(x);
    unsigned t = u & 0xffff0000u;
    h = (short)(t >> 16);
    float r = x - __uint_as_float(t);
    l = (short)(__float_as_uint(r) >> 16);
}

__device__ __forceinline__ void split_f4x2(float4 a, float4 b, short8& hi, short8& lo) {
    short h0,h1,h2,h3,h4,h5,h6,h7, l0,l1,l2,l3,l4,l5,l6,l7;
    split2(a.x,h0,l0); split2(a.y,h1,l1); split2(a.z,h2,l2); split2(a.w,h3,l3);
    split2(b.x,h4,l4); split2(b.y,h5,l5); split2(b.z,h6,l6); split2(b.w,h7,l7);
    hi = (short8){h0,h1,h2,h3,h4,h5,h6,h7};
    lo = (short8){l0,l1,l2,l3,l4,l5,l6,l7};
}

// ============================================================================
// V4 PATH: prep -> xv3 (4x vt-reuse in registers) -> reduce_t -> tu3 (4x u-reuse)
// ============================================================================

// blocks 0..255:   V[k][r] fp32 -> vt_hi/lo[r][k] bf16 (transposed)
// blocks 256..511: U[o][r] fp32 -> u_hi/lo[o][r] bf16 (layout preserved)
__global__ void prep_uv(const float* __restrict__ V, const float* __restrict__ U,
                        unsigned short* __restrict__ vt_hi, unsigned short* __restrict__ vt_lo,
                        unsigned short* __restrict__ u_hi,  unsigned short* __restrict__ u_lo)
{
    const int b = blockIdx.x;
    const int linear = (b & 255) * 256 + threadIdx.x;   // 0..65535
    short h[4], l[4];
    if (b < 256) {
        const int r  = linear >> 10;                    // 0..63
        const int k0 = (linear & 1023) * 4;             // 0..4092
        #pragma unroll
        for (int i = 0; i < 4; ++i)
            split2(V[(size_t)(k0 + i) * RANK + r], h[i], l[i]);
        const size_t o = (size_t)r * IN_F + k0;
        *(ushort4*)(vt_hi + o) = make_ushort4((unsigned short)h[0], (unsigned short)h[1],
                                              (unsigned short)h[2], (unsigned short)h[3]);
        *(ushort4*)(vt_lo + o) = make_ushort4((unsigned short)l[0], (unsigned short)l[1],
                                              (unsigned short)l[2], (unsigned short)l[3]);
    } else {
        const int idx = linear * 4;                     // contiguous over U
        const float4 u4 = *(const float4*)(U + idx);
        split2(u4.x, h[0], l[0]); split2(u4.y, h[1], l[1]);
        split2(u4.z, h[2], l[2]); split2(u4.w, h[3], l[3]);
        *(ushort4*)(u_hi + idx) = make_ushort4((unsigned short)h[0], (unsigned short)h[1],
                                               (unsigned short)h[2], (unsigned short)h[3]);
        *(ushort4*)(u_lo + idx) = make_ushort4((unsigned short)l[0], (unsigned short)l[1],
                                               (unsigned short)l[2], (unsigned short)l[3]);
    }
}

// Phase 1 with 4x vt fragment reuse: wave owns 64 rows; vt frags loaded once per
// k-step feed 4 m-frags. Block = 4 waves (4 k-subs of a 1024-k slice), grid =
// 128 m-groups x KSPLIT. Segment count/CU halves vs xv: predicted ~45-55us.
// launch_bounds kept loose (lesson R3: tight bounds -> spills).
__global__ __launch_bounds__(256, 2) void lowrank_xv3(
    const float* __restrict__ x,
    const unsigned short* __restrict__ vt_hi, const unsigned short* __restrict__ vt_lo,
    float* __restrict__ t_part)                         // [KSPLIT][8192][64] fp32
{
    __shared__ float part[KSPLIT][64][RANK + 4];        // 69632 B -> 2 blocks/CU

    const int tid  = threadIdx.x;
    const int wv   = tid >> 6;      // 0..3 (k-sub within block's 1024-k slice)
    const int lane = tid & 63;
    const int l15  = lane & 15;
    const int quad = lane >> 4;
    const int kq   = blockIdx.x & 3;         // K-split plane
    const int mg   = blockIdx.x >> 2;        // 0..127
    const int m0   = mg * 64;
    const int kbase = kq * 1024 + wv * 256;

    float4v acc[4][4] = {};                  // [m-frag][r-tile], 64 VGPR
    const float* xp[4];
    #pragma unroll
    for (int mf = 0; mf < 4; ++mf)
        xp[mf] = x + (size_t)(m0 + mf * 16 + l15) * IN_F + kbase + quad * 8;
    const unsigned short* vh = vt_hi + (size_t)l15 * IN_F + kbase + quad * 8;
    const unsigned short* vl = vt_lo + (size_t)l15 * IN_F + kbase + quad * 8;

    #pragma unroll
    for (int ks = 0; ks < 8; ++ks) {
        const int k0 = ks * 32;
        float4 xa[4], xb[4];
        #pragma unroll
        for (int mf = 0; mf < 4; ++mf) {     // 8 independent x loads issued first
            xa[mf] = *(const float4*)(xp[mf] + k0);
            xb[mf] = *(const float4*)(xp[mf] + k0 + 4);
        }
        short8 bh[4], bl[4];
        #pragma unroll
        for (int rt = 0; rt < 4; ++rt) {     // 8 vt loads, reused by 4 m-frags
            bh[rt] = *(const short8*)(vh + (size_t)rt * 16 * IN_F + k0);
            bl[rt] = *(const short8*)(vl + (size_t)rt * 16 * IN_F + k0);
        }
        #pragma unroll
        for (int mf = 0; mf < 4; ++mf) {
            short8 a_hi, a_lo;
            split_f4x2(xa[mf], xb[mf], a_hi, a_lo);
            #pragma unroll
            for (int rt = 0; rt < 4; ++rt) {
                acc[mf][rt] = MFMA16(a_lo, bh[rt], acc[mf][rt]);
                acc[mf][rt] = MFMA16(a_hi, bl[rt], acc[mf][rt]);
                acc[mf][rt] = MFMA16(a_hi, bh[rt], acc[mf][rt]);
            }
        }
    }

    // C/D layout: col = l15 (r within tile), row = quad*4 + reg (m within 16)
    #pragma unroll
    for (int mf = 0; mf < 4; ++mf)
        #pragma unroll
        for (int rt = 0; rt < 4; ++rt)
            #pragma unroll
            for (int rg = 0; rg < 4; ++rg)
                part[wv][mf * 16 + quad * 4 + rg][rt * 16 + l15] = acc[mf][rt][rg];
    __syncthreads();

    // Reduce the 4 k-sub partials in fp32; contiguous fp32 write of this plane.
    {
        const int e  = tid * 16;             // 4096 elems / 256 threads
        const int m  = e >> 6;
        const int r0 = e & 63;
        float* dst = t_part + (size_t)kq * (M_TOTAL * RANK)
                   + (size_t)(m0 + m) * RANK + r0;
        #pragma unroll
        for (int j = 0; j < 4; ++j) {
            float4 s = {0.f, 0.f, 0.f, 0.f};
            #pragma unroll
            for (int p = 0; p < KSPLIT; ++p) {
                const float4 v = *(const float4*)(&part[p][m][r0 + j * 4]);
                s.x += v.x; s.y += v.y; s.z += v.z; s.w += v.w;
            }
            *(float4*)(dst + j * 4) = s;
        }
    }
}

// Sum the 4 fp32 K-partials, split to bf16 hi/lo. 8MB read, 2MB write (~3us).
__global__ void reduce_t(const float* __restrict__ t_part,
                         unsigned short* __restrict__ t_hi, unsigned short* __restrict__ t_lo)
{
    const size_t e = (size_t)(blockIdx.x * 256 + threadIdx.x) * 4;  // grid 512
    float4 s = *(const float4*)(t_part + e);
    #pragma unroll
    for (int p = 1; p < KSPLIT; ++p) {
        const float4 a = *(const float4*)(t_part + (size_t)p * (M_TOTAL * RANK) + e);
        s.x += a.x; s.y += a.y; s.z += a.z; s.w += a.w;
    }
    short h[4], l[4];
    split2(s.x, h[0], l[0]); split2(s.y, h[1], l[1]);
    split2(s.z, h[2], l[2]); split2(s.w, h[3], l[3]);
    *(ushort4*)(t_hi + e) = make_ushort4((unsigned short)h[0], (unsigned short)h[1],
                                         (unsigned short)h[2], (unsigned short)h[3]);
    *(ushort4*)(t_lo + e) = make_ushort4((unsigned short)l[0], (unsigned short)l[1],
                                         (unsigned short)l[2], (unsigned short)l[3]);
}

// Phase 2 with 4x u fragment reuse: wave owns 64 rows x 128-o strip; u frags
// loaded once per o-tile feed 4 m-frags (only one acc set live -> VGPR ~120).
// Grid 1024 = 4 blocks/CU = 16 waves/CU. Predicted ~35-42us.
__global__ __launch_bounds__(256, 3) void lowrank_tu3(
    const unsigned short* __restrict__ t_hi, const unsigned short* __restrict__ t_lo,
    const unsigned short* __restrict__ u_hi, const unsigned short* __restrict__ u_lo,
    const float* __restrict__ bias, float* __restrict__ out)
{
    const int tid  = threadIdx.x;
    const int wv   = tid >> 6;            // 0..3
    const int lane = tid & 63;
    const int l15  = lane & 15;
    const int quad = lane >> 4;
    const int og   = blockIdx.x & 31;     // 32 o-groups of 128
    const int mg   = blockIdx.x >> 5;     // 32 m-groups of 256
    const int m0   = mg * 256 + wv * 64;  // wave's 64 rows
    const int o0   = og * 128;

    // A-frags (t) for all 4 m-frags, hoisted (loop-invariant over o). 64 VGPR.
    short8 ta_hi[4][2], ta_lo[4][2];
    #pragma unroll
    for (int mf = 0; mf < 4; ++mf) {
        const unsigned short* tp_h = t_hi + (size_t)(m0 + mf * 16 + l15) * RANK + quad * 8;
        const unsigned short* tp_l = t_lo + (size_t)(m0 + mf * 16 + l15) * RANK + quad * 8;
        ta_hi[mf][0] = *(const short8*)(tp_h);   ta_hi[mf][1] = *(const short8*)(tp_h + 32);
        ta_lo[mf][0] = *(const short8*)(tp_l);   ta_lo[mf][1] = *(const short8*)(tp_l + 32);
    }

    // B-frag: B[r][o=l15] = u_hi/lo[o][r], 16B contig per lane; 1-ahead prefetch.
    const unsigned short* up_h = u_hi + (size_t)(o0 + l15) * RANK + quad * 8;
    const unsigned short* up_l = u_lo + (size_t)(o0 + l15) * RANK + quad * 8;
    short8 uh0 = *(const short8*)(up_h), uh1 = *(const short8*)(up_h + 32);
    short8 ul0 = *(const short8*)(up_l), ul1 = *(const short8*)(up_l + 32);

    #pragma unroll
    for (int nt = 0; nt < 8; ++nt) {
        short8 nh0 = uh0, nh1 = uh1, nl0 = ul0, nl1 = ul1;
        if (nt < 7) {
            const int adv = (nt + 1) * 16 * RANK;
            nh0 = *(const short8*)(up_h + adv);   nh1 = *(const short8*)(up_h + adv + 32);
            nl0 = *(const short8*)(up_l + adv);   nl1 = *(const short8*)(up_l + adv + 32);
        }
        const int o = o0 + nt * 16 + l15;
        const float bv = bias[o];
        #pragma unroll
        for (int mf = 0; mf < 4; ++mf) {          // u frags reused 4x
            float4v acc = {bv, bv, bv, bv};
            acc = MFMA16(ta_lo[mf][0], uh0, acc);
            acc = MFMA16(ta_hi[mf][0], ul0, acc);
            acc = MFMA16(ta_hi[mf][0], uh0, acc);
            acc = MFMA16(ta_lo[mf][1], uh1, acc);
            acc = MFMA16(ta_hi[mf][1], ul1, acc);
            acc = MFMA16(ta_hi[mf][1], uh1, acc);
            // C/D: col = o (l15), row = quad*4 + reg. 64B contiguous per quad-row.
            float* op = out + (size_t)(m0 + mf * 16 + quad * 4) * OUT_F + o;
            op[0 * OUT_F] = acc[0];
            op[1 * OUT_F] = acc[1];
            op[2 * OUT_F] = acc[2];
            op[3 * OUT_F] = acc[3];
        }
        uh0 = nh0; uh1 = nh1; ul0 = nl0; ul1 = nl1;
    }
}

// ============================================================================
// LEGACY V2 PATH (verified @327us): xv/tu without m-reuse, used if ws < 12 MiB
// ============================================================================

__global__ __launch_bounds__(BLOCK, 4) void lowrank_xv(
    const float* __restrict__ x,
    const unsigned short* __restrict__ vt_hi, const unsigned short* __restrict__ vt_lo,
    unsigned short* __restrict__ t_hi, unsigned short* __restrict__ t_lo)
{
    __shared__ float part[NWAVES][M_TILE][RANK + 4];

    const int tid  = threadIdx.x;
    const int wv   = tid >> 6;
    const int lane = tid & 63;
    const int l15  = lane & 15;
    const int quad = lane >> 4;
    const int m0   = blockIdx.x * M_TILE;

    float4v acc[4] = {};
    const float*          xp = x     + (size_t)(m0 + l15) * IN_F + wv * 512 + quad * 8;
    const unsigned short* vh = vt_hi + (size_t)l15 * IN_F + wv * 512 + quad * 8;
    const unsigned short* vl = vt_lo + (size_t)l15 * IN_F + wv * 512 + quad * 8;

    float4 xa = *(const float4*)(xp);
    float4 xb = *(const float4*)(xp + 4);
    #pragma unroll
    for (int ks = 0; ks < 16; ++ks) {
        const int k0 = ks * 32;
        float4 na = xa, nb = xb;
        if (ks < 15) {
            na = *(const float4*)(xp + k0 + 32);
            nb = *(const float4*)(xp + k0 + 36);
        }
        short8 a_hi, a_lo;
        split_f4x2(xa, xb, a_hi, a_lo);
        #pragma unroll
        for (int rt = 0; rt < 4; ++rt) {
            short8 b_hi = *(const short8*)(vh + (size_t)rt * 16 * IN_F + k0);
            short8 b_lo = *(const short8*)(vl + (size_t)rt * 16 * IN_F + k0);
            acc[rt] = MFMA16(a_lo, b_hi, acc[rt]);
            acc[rt] = MFMA16(a_hi, b_lo, acc[rt]);
            acc[rt] = MFMA16(a_hi, b_hi, acc[rt]);
        }
        xa = na; xb = nb;
    }

    #pragma unroll
    for (int rt = 0; rt < 4; ++rt)
        #pragma unroll
        for (int rg = 0; rg < 4; ++rg)
            part[wv][quad * 4 + rg][rt * 16 + l15] = acc[rt][rg];
    __syncthreads();

    const int e = tid * 2;
    const int m = e >> 6, r = e & 63;
    float s0 = 0.f, s1 = 0.f;
    #pragma unroll
    for (int w = 0; w < NWAVES; ++w) { s0 += part[w][m][r]; s1 += part[w][m][r + 1]; }
    short h0, l0, h1, l1;
    split2(s0, h0, l0); split2(s1, h1, l1);
    const size_t off = (size_t)m0 * RANK + e;
    *(ushort2*)(t_hi + off) = make_ushort2((unsigned short)h0, (unsigned short)h1);
    *(ushort2*)(t_lo + off) = make_ushort2((unsigned short)l0, (unsigned short)l1);
}

__global__ __launch_bounds__(256, 4) void lowrank_tu(
    const unsigned short* __restrict__ t_hi, const unsigned short* __restrict__ t_lo,
    const unsigned short* __restrict__ u_hi, const unsigned short* __restrict__ u_lo,
    const float* __restrict__ bias, float* __restrict__ out)
{
    const int tid  = threadIdx.x;
    const int wv   = tid >> 6;
    const int lane = tid & 63;
    const int l15  = lane & 15;
    const int quad = lane >> 4;
    const int og   = blockIdx.x & 7;
    const int mg   = blockIdx.x >> 3;
    const int m0   = mg * 64 + wv * 16;
    const int o0   = og * 512;

    short8 ta_hi[2], ta_lo[2];
    {
        const unsigned short* tp_h = t_hi + (size_t)(m0 + l15) * RANK + quad * 8;
        const unsigned short* tp_l = t_lo + (size_t)(m0 + l15) * RANK + quad * 8;
        ta_hi[0] = *(const short8*)(tp_h);   ta_hi[1] = *(const short8*)(tp_h + 32);
        ta_lo[0] = *(const short8*)(tp_l);   ta_lo[1] = *(const short8*)(tp_l + 32);
    }

    #pragma unroll 2
    for (int nt = 0; nt < 32; ++nt) {
        const int o = o0 + nt * 16 + l15;
        const unsigned short* up_h = u_hi + (size_t)o * RANK + quad * 8;
        const unsigned short* up_l = u_lo + (size_t)o * RANK + quad * 8;
        const float bv = bias[o];
        float4v acc = {bv, bv, bv, bv};
        #pragma unroll
        for (int ks = 0; ks < 2; ++ks) {
            short8 uh = *(const short8*)(up_h + ks * 32);
            short8 ul = *(const short8*)(up_l + ks * 32);
            acc = MFMA16(ta_lo[ks], uh, acc);
            acc = MFMA16(ta_hi[ks], ul, acc);
            acc = MFMA16(ta_hi[ks], uh, acc);
        }
        float* op = out + (size_t)(m0 + quad * 4) * OUT_F + o;
        op[0 * OUT_F] = acc[0];
        op[1 * OUT_F] = acc[1];
        op[2 * OUT_F] = acc[2];
        op[3 * OUT_F] = acc[3];
    }
}

// ---------------- Fallback (fp32) if ws is too small ----------------
__global__ __launch_bounds__(256, 2) void fallback_fp32(
    const float* __restrict__ x, const float* __restrict__ U,
    const float* __restrict__ V, const float* __restrict__ bias,
    float* __restrict__ out)
{
    __shared__ float v_lds[128][RANK];
    __shared__ float t_lds[8][RANK];
    const int tid = threadIdx.x, lane = tid & 63, wave = tid >> 6;
    const int m0 = blockIdx.x * 8;
    float acc0 = 0.f, acc1 = 0.f;
    const size_t row_base = (size_t)(m0 + wave * 2) * IN_F;
    for (int kt = 0; kt < IN_F; kt += 128) {
        const float4* Vg = (const float4*)(V + (size_t)kt * RANK);
        float4* Vs = (float4*)(&v_lds[0][0]);
        #pragma unroll
        for (int i = 0; i < 8; ++i) Vs[tid + 256 * i] = Vg[tid + 256 * i];
        __syncthreads();
        const float* xp = x + row_base + kt;
        #pragma unroll 8
        for (int k = 0; k < 128; k += 4) {
            float v0 = v_lds[k+0][lane], v1 = v_lds[k+1][lane];
            float v2 = v_lds[k+2][lane], v3 = v_lds[k+3][lane];
            float4 xa = *(const float4*)(xp + 0 * IN_F + k);
            float4 xb = *(const float4*)(xp + 1 * IN_F + k);
            acc0 += xa.x*v0 + xa.y*v1 + xa.z*v2 + xa.w*v3;
            acc1 += xb.x*v0 + xb.y*v1 + xb.z*v2 + xb.w*v3;
        }
        __syncthreads();
    }
    t_lds[wave*2+0][lane] = acc0;
    t_lds[wave*2+1][lane] = acc1;
    __syncthreads();
    for (int oc = 0; oc < OUT_F; oc += 1024) {
        const int o4 = oc + tid * 4;
        const float4 b4 = *(const float4*)(bias + o4);
        float4 a0=b4,a1=b4,a2=b4,a3=b4,a4=b4,a5=b4,a6=b4,a7=b4;
        const float* Up = U + (size_t)o4 * RANK;
        #pragma unroll 2
        for (int r0 = 0; r0 < RANK; r0 += 4) {
            const float4 u0 = *(const float4*)(Up + 0*RANK + r0);
            const float4 u1 = *(const float4*)(Up + 1*RANK + r0);
            const float4 u2 = *(const float4*)(Up + 2*RANK + r0);
            const float4 u3 = *(const float4*)(Up + 3*RANK + r0);
            #define P2_STEP(AM, MM) { \
                const float4 t4 = *(const float4*)(&t_lds[MM][r0]); \
                AM.x += t4.x*u0.x + t4.y*u0.y + t4.z*u0.z + t4.w*u0.w; \
                AM.y += t4.x*u1.x + t4.y*u1.y + t4.z*u1.z + t4.w*u1.w; \
                AM.z += t4.x*u2.x + t4.y*u2.y + t4.z*u2.z + t4.w*u2.w; \
                AM.w += t4.x*u3.x + t4.y*u3.y + t4.z*u3.z + t4.w*u3.w; }
            P2_STEP(a0,0) P2_STEP(a1,1) P2_STEP(a2,2) P2_STEP(a3,3)
            P2_STEP(a4,4) P2_STEP(a5,5) P2_STEP(a6,6) P2_STEP(a7,7)
            #undef P2_STEP
        }
        float* op = out + (size_t)m0 * OUT_F + o4;
        *(float4*)(op+0*OUT_F)=a0; *(float4*)(op+1*OUT_F)=a1;
        *(float4*)(op+2*OUT_F)=a2; *(float4*)(op+3*OUT_F)=a3;
        *(float4*)(op+4*OUT_F)=a4; *(float4*)(op+5*OUT_F)=a5;
        *(float4*)(op+6*OUT_F)=a6; *(float4*)(op+7*OUT_F)=a7;
    }
}

extern "C" void kernel_launch(void* const* d_in, const int* in_sizes, int n_in,
                              void* d_out, int out_size, void* d_ws, size_t ws_size,
                              hipStream_t stream) {
    const float* x    = (const float*)d_in[0];
    const float* U    = (const float*)d_in[1];
    const float* V    = (const float*)d_in[2];
    const float* bias = (const float*)d_in[3];
    float* out = (float*)d_out;

    const size_t E = (size_t)RANK * IN_F;        // 262144 (V / U split planes)
    const size_t T = (size_t)M_TOTAL * RANK;     // 524288 (t planes)
    const size_t need_v4 = (E * 4 + T * 2) * sizeof(unsigned short)
                         + (size_t)KSPLIT * T * sizeof(float);           // 12 MiB
    const size_t need_v2 = (E * 4 + T * 2) * sizeof(unsigned short);     // 4 MiB

    if (ws_size >= need_v4) {
        unsigned short* vt_hi = (unsigned short*)d_ws;
        unsigned short* vt_lo = vt_hi + E;
        unsigned short* u_hi  = vt_lo + E;
        unsigned short* u_lo  = u_hi  + E;
        unsigned short* t_hi  = u_lo  + E;
        unsigned short* t_lo  = t_hi  + T;
        float*          t_part = (float*)(t_lo + T);
        prep_uv<<<dim3(512), dim3(256), 0, stream>>>(V, U, vt_hi, vt_lo, u_hi, u_lo);
        lowrank_xv3<<<dim3((M_TOTAL / 64) * KSPLIT), dim3(256), 0, stream>>>(
            x, vt_hi, vt_lo, t_part);
        reduce_t<<<dim3(T / (256 * 4)), dim3(256), 0, stream>>>(t_part, t_hi, t_lo);
        lowrank_tu3<<<dim3((M_TOTAL / 256) * (OUT_F / 128)), dim3(256), 0, stream>>>(
            t_hi, t_lo, u_hi, u_lo, bias, out);
    } else if (ws_size >= need_v2) {
        unsigned short* vt_hi = (unsigned short*)d_ws;
        unsigned short* vt_lo = vt_hi + E;
        unsigned short* u_hi  = vt_lo + E;
        unsigned short* u_lo  = u_hi  + E;
        unsigned short* t_hi  = u_lo  + E;
        unsigned short* t_lo  = t_hi  + T;
        prep_uv<<<dim3(512), dim3(256), 0, stream>>>(V, U, vt_hi, vt_lo, u_hi, u_lo);
        lowrank_xv<<<dim3(M_TOTAL / M_TILE), dim3(BLOCK), 0, stream>>>(
            x, vt_hi, vt_lo, t_hi, t_lo);
        lowrank_tu<<<dim3((M_TOTAL / 64) * (OUT_F / 512)), dim3(256), 0, stream>>>(
            t_hi, t_lo, u_hi, u_lo, bias, out);
    } else {
        fallback_fp32<<<dim3(M_TOTAL / 8), dim3(256), 0, stream>>>(x, U, V, bias, out);
    }
}